// Round 15
// baseline (180.015 us; speedup 1.0000x reference)
//
#include <hip/hip_runtime.h>

typedef __attribute__((ext_vector_type(8))) __bf16 bf16x8;
typedef __attribute__((ext_vector_type(4))) __bf16 bf16x4;
typedef __attribute__((ext_vector_type(4))) float f32x4;

// async global->LDS, 16B per lane; lds base must be wave-uniform (lane i
// lands at base + i*16)  [m97/m104 semantics]
__device__ __forceinline__ void async_copy16(const void* g, void* l) {
    __builtin_amdgcn_global_load_lds(
        (const __attribute__((address_space(1))) void*)g,
        (__attribute__((address_space(3))) void*)l, 16, 0, 0);
}

// ---------------------------------------------------------------------------
// Fused prep: [0,2048) cast x fp32->bf16; [2048,5120) transpose w_attn;
// [5120,6144) transpose w_proj. Block-uniform branching.
// ---------------------------------------------------------------------------
__global__ __launch_bounds__(256) void prep_k(
    const float* __restrict__ x, __bf16* __restrict__ xb,
    const float* __restrict__ wa, __bf16* __restrict__ wAt,
    const float* __restrict__ wp, __bf16* __restrict__ wPt)
{
    __shared__ float tile[32][33];
    const int bx = blockIdx.x;
    if (bx < 2048) {
        size_t i = ((size_t)bx * 256 + threadIdx.x) * 8;
        float4 a = *(const float4*)&x[i];
        float4 b = *(const float4*)&x[i + 4];
        bf16x8 o;
        o[0] = (__bf16)a.x; o[1] = (__bf16)a.y; o[2] = (__bf16)a.z; o[3] = (__bf16)a.w;
        o[4] = (__bf16)b.x; o[5] = (__bf16)b.y; o[6] = (__bf16)b.z; o[7] = (__bf16)b.w;
        *(bf16x8*)&xb[i] = o;
        return;
    }
    const float* src; __bf16* dst; int R, C, c0, r0;
    if (bx < 5120) {
        int id = bx - 2048;
        src = wa; dst = wAt; R = 1024; C = 3072;
        c0 = (id % 96) * 32; r0 = (id / 96) * 32;
    } else {
        int id = bx - 5120;
        src = wp; dst = wPt; R = 1024; C = 1024;
        c0 = (id & 31) * 32; r0 = (id >> 5) * 32;
    }
    int tx = threadIdx.x & 31, ty = threadIdx.x >> 5;  // 32 x 8
    for (int i = ty; i < 32; i += 8)
        tile[i][tx] = src[(size_t)(r0 + i) * C + (c0 + tx)];
    __syncthreads();
    for (int i = ty; i < 32; i += 8)
        dst[(size_t)(c0 + i) * R + (r0 + tx)] = (__bf16)tile[tx][i];
}

// ---------------------------------------------------------------------------
// BT-GEMM v2: C[M,Nc] = A[M,K] @ Bt[Nc,K]^T + bias[Nc]  (A,Bt bf16; bias f32)
// 128xTN tile, BK=32, 256 threads (4 waves), double-buffered one-barrier
// K-loop (r14). LDS: 128B lines, line L holds k-rows 2L,2L+1; granule c at
// pos c^(L&7) -> reads 2-way (free) [m136].
// MODE 0 (TN=128): scatter epilogue into Qh/Kh (b,h,m,d) and Vt (b,h,d,m');
//   Q scaled by log2e/8; Vt bf16x4 stores with the 64-key interleave
//   m' = tp*32+quad*8+h*4+r  (k = tp*32+h*16+quad*4+r).
// MODE 1: plain row-major fp32 output to Of.
// ---------------------------------------------------------------------------
template <int MODE, int TN>
__global__ __launch_bounds__(256) void gemm_bt(
    const __bf16* __restrict__ A, const __bf16* __restrict__ Bt,
    const float* __restrict__ bias, int K,
    __bf16* __restrict__ O0, __bf16* __restrict__ O1, __bf16* __restrict__ O2,
    float* __restrict__ Of)
{
    constexpr int NJ = TN / 32;                 // j-tiles per wave
    __shared__ __align__(16) __bf16 lds_a[2][128 * 32];
    __shared__ __align__(16) __bf16 lds_b[2][TN * 32];
    const int row0 = blockIdx.x * 128;
    const int col0 = blockIdx.y * TN;
    const int tid  = threadIdx.x;
    const int lane = tid & 63;
    const int w    = tid >> 6;
    const int wm   = (w >> 1) * 64, wn = (w & 1) * (TN / 2);
    const int quad = lane >> 4, l16 = lane & 15;

    auto stage = [&](int pb, int kb) {
#pragma unroll
        for (int t = 0; t < 2; ++t) {
            int s = t * 256 + tid;
            int L = s >> 3, c = (s & 7) ^ (L & 7);
            int row = 2 * L + (c >> 2), ch = c & 3;
            async_copy16(&A[(size_t)(row0 + row) * K + kb + ch * 8],
                         (char*)&lds_a[pb][0] + (t * 256 + w * 64) * 16);
        }
#pragma unroll
        for (int t = 0; t < TN / 64; ++t) {
            int s = t * 256 + tid;
            int L = s >> 3, c = (s & 7) ^ (L & 7);
            int row = 2 * L + (c >> 2), ch = c & 3;
            async_copy16(&Bt[(size_t)(col0 + row) * K + kb + ch * 8],
                         (char*)&lds_b[pb][0] + (t * 256 + w * 64) * 16);
        }
    };

    const int nIter = K >> 5;
    f32x4 acc[4][NJ] = {};
    stage(0, 0);
    for (int it = 0; it < nIter; ++it) {
        __syncthreads();
        if (it + 1 < nIter) stage((it + 1) & 1, (it + 1) << 5);
        const __bf16* la = &lds_a[it & 1][0];
        const __bf16* lb = &lds_b[it & 1][0];
        bf16x8 af[4], bfr[NJ];
#pragma unroll
        for (int i = 0; i < 4; ++i) {
            int r = wm + i * 16 + l16;
            int L = r >> 1, g = ((r & 1) * 4 + quad) ^ (L & 7);
            af[i] = *(const bf16x8*)&la[L * 64 + g * 8];
        }
#pragma unroll
        for (int j = 0; j < NJ; ++j) {
            int r = wn + j * 16 + l16;
            int L = r >> 1, g = ((r & 1) * 4 + quad) ^ (L & 7);
            bfr[j] = *(const bf16x8*)&lb[L * 64 + g * 8];
        }
#pragma unroll
        for (int i = 0; i < 4; ++i)
#pragma unroll
            for (int j = 0; j < NJ; ++j)
                acc[i][j] = __builtin_amdgcn_mfma_f32_16x16x32_bf16(
                    af[i], bfr[j], acc[i][j], 0, 0, 0);
    }

    // epilogue: C/D layout col = lane&15, row = quad*4 + reg  [m89/m91]
#pragma unroll
    for (int i = 0; i < 4; ++i) {
        int grow = row0 + wm + i * 16 + quad * 4;
#pragma unroll
        for (int j = 0; j < NJ; ++j) {
            int gcol = col0 + wn + j * 16 + l16;
            float bv = bias[gcol];
            if constexpr (MODE == 0) {
                int which = gcol >> 10;       // 0=q 1=k 2=v
                int n  = gcol & 1023;
                int hh = n >> 6, dd = n & 63;
                int bb = grow >> 11, mm0 = grow & 2047;
                int bhh = bb * 16 + hh;
                if (which == 2) {
                    // key-interleave within the 64-key tile (see header)
                    int w64 = mm0 & 63;
                    int mi = (mm0 & ~63) | (w64 & 32) | ((w64 & 12) << 1)
                             | ((w64 & 16) >> 2);
                    bf16x4 pk;   // 4 consecutive m' at fixed d: one 8B store
#pragma unroll
                    for (int r = 0; r < 4; ++r)
                        pk[r] = (__bf16)(acc[i][j][r] + bv);
                    *(bf16x4*)&O2[((size_t)bhh * 64 + dd) * 2048 + mi] = pk;
                } else {
#pragma unroll
                    for (int r = 0; r < 4; ++r) {
                        float v = acc[i][j][r] + bv;
                        if (which == 0)   // fold 1/sqrt(64) * log2(e)
                            O0[((size_t)bhh * 2048 + mm0 + r) * 64 + dd] =
                                (__bf16)(v * 0.18033688011112042f);
                        else
                            O1[((size_t)bhh * 2048 + mm0 + r) * 64 + dd] =
                                (__bf16)v;
                    }
                }
            } else {
#pragma unroll
                for (int r = 0; r < 4; ++r) {
                    int gr = grow + r;
                    Of[(size_t)gr * 1024 + gcol] = acc[i][j][r] + bv;
                }
            }
        }
    }
}

// ---------------------------------------------------------------------------
// Flash attention v8 (causal), split-K for long tiles. Grid (32 bh, 48 y):
//   y in [0,32):  qt = 31 - (y>>1), part = y&1 — SPLIT tiles (qt>=16):
//                 partA keys [0, half*64), partB keys [half*64, (qt+1)*64),
//                 half = (qt+1)>>1. Both write UNNORMALIZED numerators
//                 (shift-free softmax => partials are additive): partA into
//                 the ctx rows, partB into pnum scratch; l's into lbuf.
//   y in [32,48): qt = 47 - y (15..0) — unsplit, normalized ctx write.
// Longest block drops 33 -> 17 iters (tail-latency fix). XCD = bh&7 kept.
// S^T = K.Q^T (P in-lane); PV + row-sum now K=32 MFMA (10 instead of 20):
// the r12 Vt key-interleave makes concat(pf[2tp],pf[2tp+1]) a legal K=32
// B-frag and the full b128 V-granule the matching A-frag.
// ---------------------------------------------------------------------------
__global__ __launch_bounds__(256) void attn_kernel(
    const __bf16* __restrict__ Qh, const __bf16* __restrict__ Kh,
    const __bf16* __restrict__ Vt, __bf16* __restrict__ ctx,
    __bf16* __restrict__ pnum, float* __restrict__ lbuf)
{
    const int M = 2048, D = 64;
    const int bh = blockIdx.x;
    const int y = blockIdx.y;
    const int b = bh >> 4, h = bh & 15;
    const int tid = threadIdx.x, lane = tid & 63, w = tid >> 6;
    const int quad = lane >> 4, l16 = lane & 15;

    int qt, part, t0, t1;
    bool split;
    if (y < 32) {
        qt = 31 - (y >> 1); part = y & 1; split = true;
        int half = (qt + 1) >> 1;
        t0 = part ? half : 0;
        t1 = part ? (qt + 1) : half;
    } else {
        qt = 47 - y; part = 0; split = false;
        t0 = 0; t1 = qt + 1;
    }
    const int q0 = qt * 64;
    const int nIter = t1 - t0;

    __shared__ __align__(16) __bf16 lds_k[2][64 * 64];   // [key][d], swizzled
    __shared__ __align__(16) __bf16 lds_v[2][64 * 64];   // [d][m'], swizzled

    const __bf16* Qp = Qh + (size_t)bh * M * D;
    const __bf16* Kp = Kh + (size_t)bh * M * D;
    const __bf16* Vp = Vt + (size_t)bh * D * M;

    const int qw = q0 + w * 16;               // wave's q-base; lane q = qw+l16

    bf16x8 qf[2];
#pragma unroll
    for (int c = 0; c < 2; ++c)
        qf[c] = *(const bf16x8*)
            &Qp[(size_t)(qw + l16) * D + c * 32 + quad * 8];

    f32x4 acc2[4] = {};     // ctx^T: [f] d-tiles; col=q=l16, row=quad*4+r=d
    f32x4 acc_s = {};       // row-sums l[q]; all regs identical
    const __bf16 onev = (__bf16)1.0f;
    const bf16x8 ones8 = {onev, onev, onev, onev, onev, onev, onev, onev};

    auto stage = [&](int pb, int kb) {
#pragma unroll
        for (int t = 0; t < 2; ++t) {
            int c = w * 128 + t * 64 + lane;
            int row = c >> 3, ch = c & 7;
            int gch = ch ^ (row & 7);
            async_copy16(&Kp[(size_t)(kb + row) * 64 + gch * 8],
                         (char*)&lds_k[pb][0] + (w * 128 + t * 64) * 16);
            async_copy16(&Vp[(size_t)row * M + kb + gch * 8],
                         (char*)&lds_v[pb][0] + (w * 128 + t * 64) * 16);
        }
    };

    stage(0, t0 << 6);

    for (int i = 0; i < nIter; ++i) {
        const int kb = (t0 + i) << 6;
        __syncthreads();
        if (i + 1 < nIter) stage((i + 1) & 1, kb + 64);
        if (kb > qw + 15) continue;          // wave done (wave-uniform)
        const __bf16* kt = &lds_k[i & 1][0];
        const __bf16* vt = &lds_v[i & 1][0];

        // S^T[64k x 16q] = K Q^T : 4 key-tiles (rows) x 2 d-chunks
        f32x4 s[4];
#pragma unroll
        for (int t = 0; t < 4; ++t) {
            f32x4 tt = {};
#pragma unroll
            for (int c = 0; c < 2; ++c) {
                int ch = ((c << 2) + quad) ^ (l16 & 7);
                bf16x8 kf = *(const bf16x8*)
                    &kt[(((t << 4) + l16) << 6) + (ch << 3)];
                tt = __builtin_amdgcn_mfma_f32_16x16x32_bf16(
                    kf, qf[c], tt, 0, 0, 0);    // A=K rows, B=Q rows
            }
            s[t] = tt;
        }
        if (kb + 63 > qw) {                  // causal boundary tile
#pragma unroll
            for (int t = 0; t < 4; ++t)
#pragma unroll
                for (int r = 0; r < 4; ++r)
                    if (kb + t * 16 + quad * 4 + r > qw + l16)
                        s[t][r] = -1e30f;
        }
        // p = exp2(s); pack two C/D tiles -> one K=32 B-frag (interleaved
        // key order matches Vt's m' layout)
        bf16x8 pf32[2];
#pragma unroll
        for (int tp = 0; tp < 2; ++tp) {
            bf16x8 pp;
#pragma unroll
            for (int r = 0; r < 4; ++r) {
                pp[r]     = (__bf16)exp2f(s[2 * tp][r]);
                pp[4 + r] = (__bf16)exp2f(s[2 * tp + 1][r]);
            }
            pf32[tp] = pp;
        }
        // ctx^T += V P (K=32): full b128 granule = A-frag; l += 1.P
#pragma unroll
        for (int f = 0; f < 4; ++f) {
            int row = (f << 4) + l16;        // Vt row = d
#pragma unroll
            for (int tp = 0; tp < 2; ++tp) {
                int g = ((tp << 2) + quad) ^ (row & 7);
                bf16x8 vv = *(const bf16x8*)&vt[(row << 6) + (g << 3)];
                acc2[f] = __builtin_amdgcn_mfma_f32_16x16x32_bf16(
                    vv, pf32[tp], acc2[f], 0, 0, 0);
            }
        }
#pragma unroll
        for (int tp = 0; tp < 2; ++tp)
            acc_s = __builtin_amdgcn_mfma_f32_16x16x32_bf16(
                ones8, pf32[tp], acc_s, 0, 0, 0);
    }

    // epilogue: (numerator or normalized) -> transpose via dead LDS -> store
    __syncthreads();                          // all waves done with lds_k/v
    __bf16* ldsT = &lds_k[0][0];              // 64 x 72 bf16 = 9216 B
    const float l = acc_s[0];                 // l[q=l16] (reg-independent)
    const int tileIdx = bh * 16 + (qt - 16);  // valid only when split
    if (split && quad == 0)
        lbuf[tileIdx * 128 + part * 64 + w * 16 + l16] = l;
#pragma unroll
    for (int f = 0; f < 4; ++f) {
        bf16x4 ov;
#pragma unroll
        for (int r = 0; r < 4; ++r) {
            float v = acc2[f][r];
            ov[r] = (__bf16)(split ? v : v / l);
        }
        *(bf16x4*)&ldsT[(w * 16 + l16) * 72 + f * 16 + quad * 4] = ov;
    }
    __syncthreads();
    {
        int qq = tid >> 2;                    // 0..63
        int dp = (tid & 3) * 16;              // 0,16,32,48
        const __bf16* src = &ldsT[qq * 72 + dp];
        __bf16* dst;
        if (split && part == 1)
            dst = &pnum[(size_t)tileIdx * 4096 + qq * 64 + dp];
        else
            dst = &ctx[((size_t)(b * 2048 + q0 + qq)) * 1024 + h * 64 + dp];
        *(bf16x8*)&dst[0] = *(const bf16x8*)&src[0];
        *(bf16x8*)&dst[8] = *(const bf16x8*)&src[8];
    }
}

// ---------------------------------------------------------------------------
// Combine split partials: ctx_rows = (numA(in ctx) + numB(in pnum)) / (lA+lB)
// Grid (32 bh, 16 t), 256 thr; tile qt = 16+t.
// ---------------------------------------------------------------------------
__global__ __launch_bounds__(256) void combine_k(
    __bf16* __restrict__ ctx, const __bf16* __restrict__ pnum,
    const float* __restrict__ lbuf)
{
    const int bh = blockIdx.x, t = blockIdx.y;
    const int b = bh >> 4, h = bh & 15;
    const int tileIdx = bh * 16 + t;
    const int q0 = (16 + t) * 64;
    const int tid = threadIdx.x;
    const int qq = tid >> 2, dp = (tid & 3) * 16;

    float la = lbuf[tileIdx * 128 + qq];
    float lb = lbuf[tileIdx * 128 + 64 + qq];
    float inv = 1.0f / (la + lb);

    __bf16* crow = &ctx[((size_t)(b * 2048 + q0 + qq)) * 1024 + h * 64 + dp];
    const __bf16* prow = &pnum[(size_t)tileIdx * 4096 + qq * 64 + dp];
    bf16x8 a0 = *(const bf16x8*)&crow[0], a1 = *(const bf16x8*)&crow[8];
    bf16x8 b0 = *(const bf16x8*)&prow[0], b1 = *(const bf16x8*)&prow[8];
    bf16x8 o0, o1;
#pragma unroll
    for (int e = 0; e < 8; ++e) {
        o0[e] = (__bf16)(((float)a0[e] + (float)b0[e]) * inv);
        o1[e] = (__bf16)(((float)a1[e] + (float)b1[e]) * inv);
    }
    *(bf16x8*)&crow[0] = o0;
    *(bf16x8*)&crow[8] = o1;
}

// ---------------------------------------------------------------------------
// Workspace 24 MB:
//   ws[ 0M.. 8M): xb (bf16 x), later overwritten by ctx (attn output)
//   ws[ 8M..12M): wAt (first 4MB), dead after gemm<0> -> pnum (partB nums)
//   ws[12M..12.25M): lbuf (l partials, 256 KB) — also inside dead wAt
//   ws[ 8M..14M): wAt  (w_attn^T bf16) during prep/gemm<0>
//   ws[14M..16M): wPt  (w_proj^T bf16)
//   ws[16M..24M): Vt   [32,64,2048] bf16 (key-interleaved per 64-key tile)
// d_out doubles as scratch: Qh [0..8M), Kh [8M..16M) bf16, fully overwritten
// by the final fp32 projection (which never reads d_out).
// ---------------------------------------------------------------------------
extern "C" void kernel_launch(void* const* d_in, const int* in_sizes, int n_in,
                              void* d_out, int out_size, void* d_ws, size_t ws_size,
                              hipStream_t stream) {
    const float* x      = (const float*)d_in[0];
    const float* w_attn = (const float*)d_in[1];
    const float* w_proj = (const float*)d_in[2];
    const float* b_attn = (const float*)d_in[3];
    const float* b_proj = (const float*)d_in[4];
    float* out = (float*)d_out;

    char* ws = (char*)d_ws;
    __bf16* xb   = (__bf16*)(ws);
    __bf16* ctx  = (__bf16*)(ws);                   // aliases xb (xb dead)
    __bf16* wAt  = (__bf16*)(ws + 8388608);
    __bf16* pnum = (__bf16*)(ws + 8388608);         // aliases wAt (dead)
    float*  lbuf = (float*)(ws + 12582912);         // aliases wAt tail
    __bf16* wPt  = (__bf16*)(ws + 14680064);
    __bf16* Vt   = (__bf16*)(ws + 16777216);
    __bf16* Qh   = (__bf16*)d_out;
    __bf16* Kh   = (__bf16*)d_out + 4194304;

    prep_k<<<6144, 256, 0, stream>>>(x, xb, w_attn, wAt, w_proj, wPt);
    gemm_bt<0, 128><<<dim3(32, 24), 256, 0, stream>>>(xb, wAt, b_attn, 1024,
                                                      Qh, Kh, Vt, nullptr);
    attn_kernel<<<dim3(32, 48), 256, 0, stream>>>(Qh, Kh, Vt, ctx, pnum, lbuf);
    combine_k<<<dim3(32, 16), 256, 0, stream>>>(ctx, pnum, lbuf);
    gemm_bt<1, 64><<<dim3(32, 16), 256, 0, stream>>>(ctx, wPt, b_proj, 1024,
                                                     nullptr, nullptr, nullptr, out);
}

// Round 16
// 174.308 us; speedup vs baseline: 1.0327x; 1.0327x over previous
//
#include <hip/hip_runtime.h>

typedef __attribute__((ext_vector_type(8))) __bf16 bf16x8;
typedef __attribute__((ext_vector_type(4))) __bf16 bf16x4;
typedef __attribute__((ext_vector_type(4))) float f32x4;

// async global->LDS, 16B per lane; lds base must be wave-uniform (lane i
// lands at base + i*16)  [m97/m104 semantics]
__device__ __forceinline__ void async_copy16(const void* g, void* l) {
    __builtin_amdgcn_global_load_lds(
        (const __attribute__((address_space(1))) void*)g,
        (__attribute__((address_space(3))) void*)l, 16, 0, 0);
}

// ---------------------------------------------------------------------------
// Fused prep: [0,2048) cast x fp32->bf16; [2048,5120) transpose w_attn;
// [5120,6144) transpose w_proj. Block-uniform branching.
// ---------------------------------------------------------------------------
__global__ __launch_bounds__(256) void prep_k(
    const float* __restrict__ x, __bf16* __restrict__ xb,
    const float* __restrict__ wa, __bf16* __restrict__ wAt,
    const float* __restrict__ wp, __bf16* __restrict__ wPt)
{
    __shared__ float tile[32][33];
    const int bx = blockIdx.x;
    if (bx < 2048) {
        size_t i = ((size_t)bx * 256 + threadIdx.x) * 8;
        float4 a = *(const float4*)&x[i];
        float4 b = *(const float4*)&x[i + 4];
        bf16x8 o;
        o[0] = (__bf16)a.x; o[1] = (__bf16)a.y; o[2] = (__bf16)a.z; o[3] = (__bf16)a.w;
        o[4] = (__bf16)b.x; o[5] = (__bf16)b.y; o[6] = (__bf16)b.z; o[7] = (__bf16)b.w;
        *(bf16x8*)&xb[i] = o;
        return;
    }
    const float* src; __bf16* dst; int R, C, c0, r0;
    if (bx < 5120) {
        int id = bx - 2048;
        src = wa; dst = wAt; R = 1024; C = 3072;
        c0 = (id % 96) * 32; r0 = (id / 96) * 32;
    } else {
        int id = bx - 5120;
        src = wp; dst = wPt; R = 1024; C = 1024;
        c0 = (id & 31) * 32; r0 = (id >> 5) * 32;
    }
    int tx = threadIdx.x & 31, ty = threadIdx.x >> 5;  // 32 x 8
    for (int i = ty; i < 32; i += 8)
        tile[i][tx] = src[(size_t)(r0 + i) * C + (c0 + tx)];
    __syncthreads();
    for (int i = ty; i < 32; i += 8)
        dst[(size_t)(c0 + i) * R + (r0 + tx)] = (__bf16)tile[tx][i];
}

// ---------------------------------------------------------------------------
// BT-GEMM v2: C[M,Nc] = A[M,K] @ Bt[Nc,K]^T + bias[Nc]  (A,Bt bf16; bias f32)
// 128xTN tile, BK=32, 256 threads (4 waves), double-buffered one-barrier
// K-loop (r14). LDS: 128B lines, line L holds k-rows 2L,2L+1; granule c at
// pos c^(L&7) -> reads 2-way (free) [m136].
// MODE 0 (TN=128): scatter epilogue into Qh/Kh (b,h,m,d) and Vt (b,h,d,m');
//   Q scaled by log2e/8; Vt bf16x4 stores with the 64-key interleave
//   m' = tp*32+quad*8+h*4+r  (k = tp*32+h*16+quad*4+r).
// MODE 1: plain row-major fp32 output to Of.
// ---------------------------------------------------------------------------
template <int MODE, int TN>
__global__ __launch_bounds__(256) void gemm_bt(
    const __bf16* __restrict__ A, const __bf16* __restrict__ Bt,
    const float* __restrict__ bias, int K,
    __bf16* __restrict__ O0, __bf16* __restrict__ O1, __bf16* __restrict__ O2,
    float* __restrict__ Of)
{
    constexpr int NJ = TN / 32;                 // j-tiles per wave
    __shared__ __align__(16) __bf16 lds_a[2][128 * 32];
    __shared__ __align__(16) __bf16 lds_b[2][TN * 32];
    const int row0 = blockIdx.x * 128;
    const int col0 = blockIdx.y * TN;
    const int tid  = threadIdx.x;
    const int lane = tid & 63;
    const int w    = tid >> 6;
    const int wm   = (w >> 1) * 64, wn = (w & 1) * (TN / 2);
    const int quad = lane >> 4, l16 = lane & 15;

    auto stage = [&](int pb, int kb) {
#pragma unroll
        for (int t = 0; t < 2; ++t) {
            int s = t * 256 + tid;
            int L = s >> 3, c = (s & 7) ^ (L & 7);
            int row = 2 * L + (c >> 2), ch = c & 3;
            async_copy16(&A[(size_t)(row0 + row) * K + kb + ch * 8],
                         (char*)&lds_a[pb][0] + (t * 256 + w * 64) * 16);
        }
#pragma unroll
        for (int t = 0; t < TN / 64; ++t) {
            int s = t * 256 + tid;
            int L = s >> 3, c = (s & 7) ^ (L & 7);
            int row = 2 * L + (c >> 2), ch = c & 3;
            async_copy16(&Bt[(size_t)(col0 + row) * K + kb + ch * 8],
                         (char*)&lds_b[pb][0] + (t * 256 + w * 64) * 16);
        }
    };

    const int nIter = K >> 5;
    f32x4 acc[4][NJ] = {};
    stage(0, 0);
    for (int it = 0; it < nIter; ++it) {
        __syncthreads();
        if (it + 1 < nIter) stage((it + 1) & 1, (it + 1) << 5);
        const __bf16* la = &lds_a[it & 1][0];
        const __bf16* lb = &lds_b[it & 1][0];
        bf16x8 af[4], bfr[NJ];
#pragma unroll
        for (int i = 0; i < 4; ++i) {
            int r = wm + i * 16 + l16;
            int L = r >> 1, g = ((r & 1) * 4 + quad) ^ (L & 7);
            af[i] = *(const bf16x8*)&la[L * 64 + g * 8];
        }
#pragma unroll
        for (int j = 0; j < NJ; ++j) {
            int r = wn + j * 16 + l16;
            int L = r >> 1, g = ((r & 1) * 4 + quad) ^ (L & 7);
            bfr[j] = *(const bf16x8*)&lb[L * 64 + g * 8];
        }
#pragma unroll
        for (int i = 0; i < 4; ++i)
#pragma unroll
            for (int j = 0; j < NJ; ++j)
                acc[i][j] = __builtin_amdgcn_mfma_f32_16x16x32_bf16(
                    af[i], bfr[j], acc[i][j], 0, 0, 0);
    }

    // epilogue: C/D layout col = lane&15, row = quad*4 + reg  [m89/m91]
#pragma unroll
    for (int i = 0; i < 4; ++i) {
        int grow = row0 + wm + i * 16 + quad * 4;
#pragma unroll
        for (int j = 0; j < NJ; ++j) {
            int gcol = col0 + wn + j * 16 + l16;
            float bv = bias[gcol];
            if constexpr (MODE == 0) {
                int which = gcol >> 10;       // 0=q 1=k 2=v
                int n  = gcol & 1023;
                int hh = n >> 6, dd = n & 63;
                int bb = grow >> 11, mm0 = grow & 2047;
                int bhh = bb * 16 + hh;
                if (which == 2) {
                    // key-interleave within the 64-key tile (see header)
                    int w64 = mm0 & 63;
                    int mi = (mm0 & ~63) | (w64 & 32) | ((w64 & 12) << 1)
                             | ((w64 & 16) >> 2);
                    bf16x4 pk;   // 4 consecutive m' at fixed d: one 8B store
#pragma unroll
                    for (int r = 0; r < 4; ++r)
                        pk[r] = (__bf16)(acc[i][j][r] + bv);
                    *(bf16x4*)&O2[((size_t)bhh * 64 + dd) * 2048 + mi] = pk;
                } else {
#pragma unroll
                    for (int r = 0; r < 4; ++r) {
                        float v = acc[i][j][r] + bv;
                        if (which == 0)   // fold 1/sqrt(64) * log2(e)
                            O0[((size_t)bhh * 2048 + mm0 + r) * 64 + dd] =
                                (__bf16)(v * 0.18033688011112042f);
                        else
                            O1[((size_t)bhh * 2048 + mm0 + r) * 64 + dd] =
                                (__bf16)v;
                    }
                }
            } else {
#pragma unroll
                for (int r = 0; r < 4; ++r) {
                    int gr = grow + r;
                    Of[(size_t)gr * 1024 + gcol] = acc[i][j][r] + bv;
                }
            }
        }
    }
}

// ---------------------------------------------------------------------------
// Flash attention v9 (causal). Grid (32 bh, 32 y), 256 thr, qt = 31 - y
// (longest first); XCD = bh & 7 -> K/V L2-resident (r7: FETCH 70->12 MB).
// S^T = K.Q^T so P lands in-lane in MFMA operand layout (no LDS round-trip).
// PV + row-sum use K=32 MFMA (10/iter, r15-verified): the Vt key-interleave
// makes concat of two C/D tiles a legal K=32 B-frag and the full b128
// V-granule the matching A-frag. Softmax p = exp2(s), shift-exact (Q
// pre-scaled by log2e/8; causal diag guarantees l >= 1).
// ---------------------------------------------------------------------------
__global__ __launch_bounds__(256) void attn_kernel(
    const __bf16* __restrict__ Qh, const __bf16* __restrict__ Kh,
    const __bf16* __restrict__ Vt, __bf16* __restrict__ ctx)
{
    const int M = 2048, D = 64;
    const int bh = blockIdx.x;
    const int qt = 31 - blockIdx.y;
    const int b = bh >> 4, h = bh & 15;
    const int tid = threadIdx.x, lane = tid & 63, w = tid >> 6;
    const int quad = lane >> 4, l16 = lane & 15;

    const int q0 = qt * 64;
    const int nIter = qt + 1;                 // 64-key tiles: 0 .. q0+63

    __shared__ __align__(16) __bf16 lds_k[2][64 * 64];   // [key][d], swizzled
    __shared__ __align__(16) __bf16 lds_v[2][64 * 64];   // [d][m'], swizzled

    const __bf16* Qp = Qh + (size_t)bh * M * D;
    const __bf16* Kp = Kh + (size_t)bh * M * D;
    const __bf16* Vp = Vt + (size_t)bh * D * M;

    const int qw = q0 + w * 16;               // wave's q-base; lane q = qw+l16

    bf16x8 qf[2];
#pragma unroll
    for (int c = 0; c < 2; ++c)
        qf[c] = *(const bf16x8*)
            &Qp[(size_t)(qw + l16) * D + c * 32 + quad * 8];

    f32x4 acc2[4] = {};     // ctx^T: [f] d-tiles; col=q=l16, row=quad*4+r=d
    f32x4 acc_s = {};       // row-sums l[q]; all regs identical
    const __bf16 onev = (__bf16)1.0f;
    const bf16x8 ones8 = {onev, onev, onev, onev, onev, onev, onev, onev};

    auto stage = [&](int pb, int kb) {
#pragma unroll
        for (int t = 0; t < 2; ++t) {
            int c = w * 128 + t * 64 + lane;
            int row = c >> 3, ch = c & 7;
            int gch = ch ^ (row & 7);
            async_copy16(&Kp[(size_t)(kb + row) * 64 + gch * 8],
                         (char*)&lds_k[pb][0] + (w * 128 + t * 64) * 16);
            async_copy16(&Vp[(size_t)row * M + kb + gch * 8],
                         (char*)&lds_v[pb][0] + (w * 128 + t * 64) * 16);
        }
    };

    stage(0, 0);

    for (int it = 0; it < nIter; ++it) {
        const int kb = it << 6;
        __syncthreads();
        if (it + 1 < nIter) stage((it + 1) & 1, kb + 64);
        const __bf16* kt = &lds_k[it & 1][0];
        const __bf16* vt = &lds_v[it & 1][0];

        // S^T[64k x 16q] = K Q^T : 4 key-tiles (rows) x 2 d-chunks
        f32x4 s[4];
#pragma unroll
        for (int t = 0; t < 4; ++t) {
            f32x4 tt = {};
#pragma unroll
            for (int c = 0; c < 2; ++c) {
                int ch = ((c << 2) + quad) ^ (l16 & 7);
                bf16x8 kf = *(const bf16x8*)
                    &kt[(((t << 4) + l16) << 6) + (ch << 3)];
                tt = __builtin_amdgcn_mfma_f32_16x16x32_bf16(
                    kf, qf[c], tt, 0, 0, 0);    // A=K rows, B=Q rows
            }
            s[t] = tt;
        }
        if (kb + 63 > qw) {                  // causal boundary tile
#pragma unroll
            for (int t = 0; t < 4; ++t)
#pragma unroll
                for (int r = 0; r < 4; ++r)
                    if (kb + t * 16 + quad * 4 + r > qw + l16)
                        s[t][r] = -1e30f;
        }
        // p = exp2(s); pack two C/D tiles -> one K=32 B-frag (interleaved
        // key order matches Vt's m' layout)
        bf16x8 pf32[2];
#pragma unroll
        for (int tp = 0; tp < 2; ++tp) {
            bf16x8 pp;
#pragma unroll
            for (int r = 0; r < 4; ++r) {
                pp[r]     = (__bf16)exp2f(s[2 * tp][r]);
                pp[4 + r] = (__bf16)exp2f(s[2 * tp + 1][r]);
            }
            pf32[tp] = pp;
        }
        // ctx^T += V P (K=32): full b128 granule = A-frag; l += 1.P
#pragma unroll
        for (int f = 0; f < 4; ++f) {
            int row = (f << 4) + l16;        // Vt row = d
#pragma unroll
            for (int tp = 0; tp < 2; ++tp) {
                int g = ((tp << 2) + quad) ^ (row & 7);
                bf16x8 vv = *(const bf16x8*)&vt[(row << 6) + (g << 3)];
                acc2[f] = __builtin_amdgcn_mfma_f32_16x16x32_bf16(
                    vv, pf32[tp], acc2[f], 0, 0, 0);
            }
        }
#pragma unroll
        for (int tp = 0; tp < 2; ++tp)
            acc_s = __builtin_amdgcn_mfma_f32_16x16x32_bf16(
                ones8, pf32[tp], acc_s, 0, 0, 0);
    }

    // epilogue: divide by l, transpose ctx^T -> ctx via dead lds_k space
    __syncthreads();                          // all waves done with lds_k/v
    __bf16* ldsT = &lds_k[0][0];              // 64 x 72 bf16 = 9216 B
    const float l = acc_s[0];                 // l[q=l16] (reg-independent)
#pragma unroll
    for (int f = 0; f < 4; ++f) {
        bf16x4 ov;
#pragma unroll
        for (int r = 0; r < 4; ++r)
            ov[r] = (__bf16)(acc2[f][r] / l);
        *(bf16x4*)&ldsT[(w * 16 + l16) * 72 + f * 16 + quad * 4] = ov;
    }
    __syncthreads();
    {
        int qq = tid >> 2;                    // 0..63
        int dp = (tid & 3) * 16;              // 0,16,32,48
        const __bf16* src = &ldsT[qq * 72 + dp];
        __bf16* dst = &ctx[((size_t)(b * 2048 + q0 + qq)) * 1024 + h * 64 + dp];
        *(bf16x8*)&dst[0] = *(const bf16x8*)&src[0];
        *(bf16x8*)&dst[8] = *(const bf16x8*)&src[8];
    }
}

// ---------------------------------------------------------------------------
// Workspace 24 MB:
//   ws[ 0M.. 8M): xb (bf16 x), later overwritten by ctx (attn output)
//   ws[ 8M..14M): wAt  (w_attn^T bf16)
//   ws[14M..16M): wPt  (w_proj^T bf16)
//   ws[16M..24M): Vt   [32,64,2048] bf16 (key-interleaved per 64-key tile)
// d_out doubles as scratch: Qh [0..8M), Kh [8M..16M) bf16, fully overwritten
// by the final fp32 projection (which never reads d_out).
// ---------------------------------------------------------------------------
extern "C" void kernel_launch(void* const* d_in, const int* in_sizes, int n_in,
                              void* d_out, int out_size, void* d_ws, size_t ws_size,
                              hipStream_t stream) {
    const float* x      = (const float*)d_in[0];
    const float* w_attn = (const float*)d_in[1];
    const float* w_proj = (const float*)d_in[2];
    const float* b_attn = (const float*)d_in[3];
    const float* b_proj = (const float*)d_in[4];
    float* out = (float*)d_out;

    char* ws = (char*)d_ws;
    __bf16* xb  = (__bf16*)(ws);
    __bf16* ctx = (__bf16*)(ws);                    // aliases xb (xb dead)
    __bf16* wAt = (__bf16*)(ws + 8388608);
    __bf16* wPt = (__bf16*)(ws + 14680064);
    __bf16* Vt  = (__bf16*)(ws + 16777216);
    __bf16* Qh  = (__bf16*)d_out;
    __bf16* Kh  = (__bf16*)d_out + 4194304;

    prep_k<<<6144, 256, 0, stream>>>(x, xb, w_attn, wAt, w_proj, wPt);
    gemm_bt<0, 128><<<dim3(32, 24), 256, 0, stream>>>(xb, wAt, b_attn, 1024,
                                                      Qh, Kh, Vt, nullptr);
    attn_kernel<<<dim3(32, 32), 256, 0, stream>>>(Qh, Kh, Vt, ctx);
    gemm_bt<1, 64><<<dim3(32, 16), 256, 0, stream>>>(ctx, wPt, b_proj, 1024,
                                                     nullptr, nullptr, nullptr, out);
}